// Round 16
// baseline (728.957 us; speedup 1.0000x reference)
//
#include <hip/hip_runtime.h>
#include <math.h>

#define NNODES 10000
#define NEDGES 40000
#define DIM 64
#define MC 4160     // 4096 h1-contraction cols + 64 bias cols
#define WS 200      // LDS row stride (ushorts) for 192-k bf16 tiles (k_node)
#define AST2 72     // LDS row stride (ushorts) for 64-k bf16 tiles (k_gemmM)

typedef short bf16x8 __attribute__((ext_vector_type(8)));
typedef float floatx4 __attribute__((ext_vector_type(4)));

__device__ __forceinline__ float sigmoidf_(float x) { return 1.0f / (1.0f + expf(-x)); }

// float -> bf16 (RNE), returned as raw ushort
__device__ __forceinline__ unsigned short f2bf(float x) {
    unsigned int u = __float_as_uint(x);
    u += 0x7fffu + ((u >> 16) & 1u);
    return (unsigned short)(u >> 16);
}
__device__ __forceinline__ float bf2f(unsigned short h) {
    return __uint_as_float(((unsigned int)h) << 16);
}
// write split [hi | hi | lo] at row base (A_cat layout for K=192 bf16 GEMM)
__device__ __forceinline__ void write_split(unsigned short* __restrict__ p, int d, float v) {
    unsigned short hi = f2bf(v);
    unsigned short lo = f2bf(v - bf2f(hi));
    p[d] = hi;
    p[64 + d] = hi;
    p[128 + d] = lo;
}

// out0 = relu(x @ lin0_w.T + lin0_b)   [N,64] ; also writes bf16-split A rows
__global__ __launch_bounds__(256) void k_node_init(const float* __restrict__ x,
                                                   const float* __restrict__ w,
                                                   const float* __restrict__ b,
                                                   float* __restrict__ out,
                                                   unsigned short* __restrict__ Abf) {
    int idx = blockIdx.x * 256 + threadIdx.x;
    if (idx >= NNODES * 64) return;
    int n = idx >> 6, d = idx & 63;
    float a = b[d];
    a += x[n * 3 + 0] * w[d * 3 + 0];
    a += x[n * 3 + 1] * w[d * 3 + 1];
    a += x[n * 3 + 2] * w[d * 3 + 2];
    float v = fmaxf(a, 0.0f);
    out[idx] = v;
    write_split(Abf + (size_t)n * 192, d, v);
}

// h1 = relu(edge_attr @ em1_w.T + em1_b), written at src-sorted position
__global__ __launch_bounds__(256) void k_h1(const float* __restrict__ ea,
                                            const float* __restrict__ w,
                                            const float* __restrict__ b,
                                            const int* __restrict__ sortpos,
                                            float* __restrict__ h1s) {
    int idx = blockIdx.x * 256 + threadIdx.x;
    if (idx >= NEDGES * 64) return;
    int e = idx >> 6, d = idx & 63;
    float a = b[d];
#pragma unroll
    for (int j = 0; j < 7; ++j) a += ea[e * 7 + j] * w[d * 7 + j];
    h1s[(size_t)sortpos[e] * 64 + d] = fmaxf(a, 0.0f);
}

// Fused weight-table build:
// blocks [0, 1040): Bbf split table (k_gemmM reads hi cols; k_msg bias col)
// blocks [1040, 1152): Wcat split tables for node-update GEMMs
__global__ __launch_bounds__(256) void k_wtab(const float* __restrict__ em2_w,
                                              const float* __restrict__ em2_b,
                                              const float* __restrict__ root_w,
                                              const float* __restrict__ wih,
                                              const float* __restrict__ whh,
                                              unsigned short* __restrict__ Bbf,
                                              unsigned short* __restrict__ Wcat) {
    if (blockIdx.x < 1040) {
        int idx = blockIdx.x * 256 + threadIdx.x;
        if (idx >= 64 * MC) return;
        int c = idx >> 6, i = idx & 63;
        float v;
        if (c < 4096) {
            v = em2_w[((size_t)(i * 64 + (c >> 6))) * 64 + (c & 63)];
        } else {
            v = em2_b[i * 64 + (c - 4096)];
        }
        unsigned short hi = f2bf(v);
        unsigned short lo = f2bf(v - bf2f(hi));
        unsigned short* row = Bbf + (size_t)c * 192;
        row[i] = hi;
        row[64 + i] = lo;
        row[128 + i] = hi;
    } else {
        int idx = (blockIdx.x - 1040) * 256 + threadIdx.x;
        if (idx >= 448 * 64) return;
        int r = idx >> 6, i = idx & 63;
        float v;
        if (r < 64) v = root_w[i * 64 + r];
        else if (r < 256) v = wih[(r - 64) * 64 + i];
        else v = whh[(r - 256) * 64 + i];
        unsigned short hi = f2bf(v);
        unsigned short lo = f2bf(v - bf2f(hi));
        unsigned short* row = Wcat + (size_t)r * 192;
        row[i] = hi;
        row[64 + i] = lo;
        row[128 + i] = hi;
    }
}

// src histogram (for CSR sort) + dst degree (for mean)
__global__ __launch_bounds__(256) void k_hist(const int* __restrict__ ei,
                                              int* __restrict__ counts,
                                              float* __restrict__ deg) {
    int e = blockIdx.x * 256 + threadIdx.x;
    if (e < NEDGES) {
        atomicAdd(&counts[ei[e]], 1);
        atomicAdd(&deg[ei[NEDGES + e]], 1.0f);
    }
}

// single-block 2-phase exclusive scan (+ folds inv-degree computation).
__global__ __launch_bounds__(256) void k_scan(const int* __restrict__ counts,
                                              int* __restrict__ row_start,
                                              int* __restrict__ cursor,
                                              const float* __restrict__ deg,
                                              float* __restrict__ invd) {
    __shared__ int partial[256];
    const int tid = threadIdx.x;
    const int base = tid * 40;            // 256*40 = 10240 >= NNODES
    int local[40];
    int sum = 0;
#pragma unroll
    for (int i = 0; i < 40; ++i) {
        int idx = base + i;
        int v = (idx < NNODES) ? counts[idx] : 0;
        local[i] = sum;
        sum += v;
    }
    partial[tid] = sum;
    __syncthreads();
    for (int off = 1; off < 256; off <<= 1) {
        int t = (tid >= off) ? partial[tid - off] : 0;
        __syncthreads();
        partial[tid] += t;
        __syncthreads();
    }
    const int prev = (tid > 0) ? partial[tid - 1] : 0;
#pragma unroll
    for (int i = 0; i < 40; ++i) {
        int idx = base + i;
        if (idx < NNODES) {
            int rs = prev + local[i];
            row_start[idx] = rs;
            cursor[idx] = rs;
            float dg = deg[idx];
            invd[idx] = dg > 0.0f ? 1.0f / dg : 0.0f;
        }
    }
    if (tid == 255) row_start[NNODES] = partial[255];
}

__global__ __launch_bounds__(256) void k_scatter(const int* __restrict__ ei,
                                                 int* __restrict__ cursor,
                                                 int* __restrict__ sortpos,
                                                 int* __restrict__ dst_s) {
    int e = blockIdx.x * 256 + threadIdx.x;
    if (e < NEDGES) {
        int s = ei[e];
        int pos = atomicAdd(&cursor[s], 1);
        sortpos[e] = pos;
        dst_s[pos] = ei[NEDGES + e];
    }
}

// M[10000, 4160] = out @ W2 via plain-bf16 MFMA, K=64, coalesced LDS staging,
// packed-bf16 epilogue (C overlays staging buffer). LDS = 18.4 KB.
__global__ __launch_bounds__(256) void k_gemmM(const unsigned short* __restrict__ Abf,
                                               const unsigned short* __restrict__ Bbf,
                                               unsigned short* __restrict__ Mb) {
    __shared__ __align__(16) unsigned short smem[2 * 64 * AST2];  // 18432 B
    unsigned short* As = smem;
    unsigned short* Bs = smem + 64 * AST2;
    const int tid = threadIdx.x;
    const int col0 = blockIdx.x * 64;
    const int row0 = blockIdx.y * 64;
#pragma unroll
    for (int j = 0; j < 2; ++j) {
        int idx = tid + 256 * j;       // 0..511
        int r = idx >> 3, c8 = (idx & 7) * 8;
        int ra = row0 + r;
        if (ra >= NNODES) ra = NNODES - 1;
        *reinterpret_cast<uint4*>(&As[r * AST2 + c8]) =
            *reinterpret_cast<const uint4*>(&Abf[(size_t)ra * 192 + c8]);
        *reinterpret_cast<uint4*>(&Bs[r * AST2 + c8]) =
            *reinterpret_cast<const uint4*>(&Bbf[(size_t)(col0 + r) * 192 + c8]);
    }
    __syncthreads();
    const int wave = tid >> 6, lane = tid & 63;
    const int mi = lane & 15, q = lane >> 4;
    floatx4 acc[4];
#pragma unroll
    for (int nt = 0; nt < 4; ++nt)
#pragma unroll
        for (int r = 0; r < 4; ++r) acc[nt][r] = 0.0f;
    const unsigned short* arow = &As[(wave * 16 + mi) * AST2 + q * 8];
#pragma unroll
    for (int ks = 0; ks < 2; ++ks) {
        bf16x8 a = *reinterpret_cast<const bf16x8*>(arow + ks * 32);
#pragma unroll
        for (int nt = 0; nt < 4; ++nt) {
            bf16x8 b = *reinterpret_cast<const bf16x8*>(&Bs[(nt * 16 + mi) * AST2 + ks * 32 + q * 8]);
            acc[nt] = __builtin_amdgcn_mfma_f32_16x16x32_bf16(a, b, acc[nt], 0, 0, 0);
        }
    }
    __syncthreads();  // staging reads done; overlay C-tile
    float* Cs = reinterpret_cast<float*>(smem);  // [64][68] floats = 17408 B
    const int rl = wave * 16 + q * 4;
#pragma unroll
    for (int nt = 0; nt < 4; ++nt)
#pragma unroll
        for (int r = 0; r < 4; ++r)
            Cs[(rl + r) * 68 + nt * 16 + mi] = acc[nt][r];
    __syncthreads();
#pragma unroll
    for (int j = 0; j < 2; ++j) {
        int idx = tid + 256 * j;        // 0..511
        int r = idx >> 3, c8 = (idx & 7) * 8;
        int row = row0 + r;
        if (row < NNODES) {
            const float* src = &Cs[r * 68 + c8];
            unsigned int p0 = (unsigned int)f2bf(src[0]) | ((unsigned int)f2bf(src[1]) << 16);
            unsigned int p1 = (unsigned int)f2bf(src[2]) | ((unsigned int)f2bf(src[3]) << 16);
            unsigned int p2 = (unsigned int)f2bf(src[4]) | ((unsigned int)f2bf(src[5]) << 16);
            unsigned int p3 = (unsigned int)f2bf(src[6]) | ((unsigned int)f2bf(src[7]) << 16);
            *reinterpret_cast<uint4*>(&Mb[(size_t)row * MC + col0 + c8]) =
                make_uint4(p0, p1, p2, p3);
        }
    }
}

// Wave-per-src message over bf16 M: lane o holds its full M row slice (8 x uint4),
// unpacks bf16 inline. No LDS, no barriers. Coalesced atomic row per edge.
__global__ __launch_bounds__(256) void k_msg(const unsigned short* __restrict__ Mb,
                                             const float* __restrict__ h1s,
                                             const int* __restrict__ row_start,
                                             const int* __restrict__ dst_s,
                                             float* __restrict__ agg) {
    const int w = threadIdx.x >> 6;
    const int o = threadIdx.x & 63;
    const int s = blockIdx.x * 4 + w;
    const int e0 = row_start[s], e1 = row_start[s + 1];
    if (e0 == e1) return;
    const unsigned short* mrow = Mb + (size_t)s * MC + o * 64;
    uint4 m[8];
#pragma unroll
    for (int j = 0; j < 8; ++j)
        m[j] = *reinterpret_cast<const uint4*>(mrow + j * 8);
    const float bias = bf2f(Mb[(size_t)s * MC + 4096 + o]);
    for (int e = e0; e < e1; ++e) {
        const float4* hv = reinterpret_cast<const float4*>(h1s + (size_t)e * 64);
        float acc = bias;
#pragma unroll
        for (int j = 0; j < 8; ++j) {
            float4 ha = hv[2 * j];
            float4 hb = hv[2 * j + 1];
            unsigned int u;
            u = m[j].x;
            acc += ha.x * __uint_as_float(u << 16) + ha.y * __uint_as_float(u & 0xffff0000u);
            u = m[j].y;
            acc += ha.z * __uint_as_float(u << 16) + ha.w * __uint_as_float(u & 0xffff0000u);
            u = m[j].z;
            acc += hb.x * __uint_as_float(u << 16) + hb.y * __uint_as_float(u & 0xffff0000u);
            u = m[j].w;
            acc += hb.z * __uint_as_float(u << 16) + hb.w * __uint_as_float(u & 0xffff0000u);
        }
        atomicAdd(&agg[(size_t)dst_s[e] * 64 + o], acc);
    }
}

// MFMA node update: 64-node tile per block; 3 GEMM phases (gh, conv, gi) + GRU epilogue.
// fp32-split K=192 path (GRU recurrence precision-critical). Zeroes agg after use.
__global__ __launch_bounds__(256) void k_node(float* __restrict__ agg,
                                              const float* __restrict__ invdeg,
                                              const unsigned short* __restrict__ Wcat,
                                              const float* __restrict__ conv_b,
                                              const float* __restrict__ bih,
                                              const float* __restrict__ bhh,
                                              float* __restrict__ out,
                                              unsigned short* __restrict__ Abf) {
    __shared__ unsigned short As[64 * WS];   // out A_cat
    __shared__ unsigned short Ms[64 * WS];   // m A_cat (written in conv phase)
    __shared__ unsigned short Bs[192 * WS];  // weight B_cat staging (whh -> root -> wih)
    __shared__ float ho[64 * 68];            // exact f32 h_old
    const int tid = threadIdx.x;
    const int row0 = blockIdx.x * 64;
#pragma unroll
    for (int j = 0; j < 6; ++j) {
        int idx = tid + 256 * j;
        int r = idx / 24, jj = idx % 24;
        int ra = row0 + r; if (ra >= NNODES) ra = NNODES - 1;
        *reinterpret_cast<uint4*>(&As[r * WS + jj * 8]) =
            *reinterpret_cast<const uint4*>(&Abf[(size_t)ra * 192 + jj * 8]);
    }
#pragma unroll
    for (int j = 0; j < 4; ++j) {
        int idx = tid + 256 * j;
        int r = idx >> 4, c4 = (idx & 15) * 4;
        int ra = row0 + r; if (ra >= NNODES) ra = NNODES - 1;
        *reinterpret_cast<float4*>(&ho[r * 68 + c4]) =
            *reinterpret_cast<const float4*>(&out[(size_t)ra * 64 + c4]);
    }
#pragma unroll
    for (int j = 0; j < 18; ++j) {
        int idx = tid + 256 * j;
        int r = idx / 24, jj = idx % 24;
        *reinterpret_cast<uint4*>(&Bs[r * WS + jj * 8]) =
            *reinterpret_cast<const uint4*>(&Wcat[(size_t)(256 + r) * 192 + jj * 8]);
    }
    __syncthreads();
    const int wave = tid >> 6, lane = tid & 63;
    const int mi = lane & 15, q = lane >> 4;
    const int d = wave * 16 + mi;
    // phase 1: gh = out @ whh.T for gate cols {d, 64+d, 128+d}
    floatx4 gh[4][3];
#pragma unroll
    for (int rt = 0; rt < 4; ++rt)
#pragma unroll
        for (int g = 0; g < 3; ++g)
#pragma unroll
            for (int r = 0; r < 4; ++r) gh[rt][g][r] = 0.0f;
#pragma unroll
    for (int ks = 0; ks < 6; ++ks) {
        bf16x8 b[3];
#pragma unroll
        for (int g = 0; g < 3; ++g)
            b[g] = *reinterpret_cast<const bf16x8*>(&Bs[(g * 64 + d) * WS + ks * 32 + q * 8]);
#pragma unroll
        for (int rt = 0; rt < 4; ++rt) {
            bf16x8 a = *reinterpret_cast<const bf16x8*>(&As[(rt * 16 + mi) * WS + ks * 32 + q * 8]);
#pragma unroll
            for (int g = 0; g < 3; ++g)
                gh[rt][g] = __builtin_amdgcn_mfma_f32_16x16x32_bf16(a, b[g], gh[rt][g], 0, 0, 0);
        }
    }
    __syncthreads();
    // restage Bs <- root
#pragma unroll
    for (int j = 0; j < 6; ++j) {
        int idx = tid + 256 * j;
        int r = idx / 24, jj = idx % 24;
        *reinterpret_cast<uint4*>(&Bs[r * WS + jj * 8]) =
            *reinterpret_cast<const uint4*>(&Wcat[(size_t)r * 192 + jj * 8]);
    }
    __syncthreads();
    // phase 2: m = relu(out@root + agg*invd + conv_b) -> Ms (A_cat split); zero agg
    {
        floatx4 cm[4];
#pragma unroll
        for (int rt = 0; rt < 4; ++rt)
#pragma unroll
            for (int r = 0; r < 4; ++r) cm[rt][r] = 0.0f;
#pragma unroll
        for (int ks = 0; ks < 6; ++ks) {
            bf16x8 b = *reinterpret_cast<const bf16x8*>(&Bs[d * WS + ks * 32 + q * 8]);
#pragma unroll
            for (int rt = 0; rt < 4; ++rt) {
                bf16x8 a = *reinterpret_cast<const bf16x8*>(&As[(rt * 16 + mi) * WS + ks * 32 + q * 8]);
                cm[rt] = __builtin_amdgcn_mfma_f32_16x16x32_bf16(a, b, cm[rt], 0, 0, 0);
            }
        }
        const float cb = conv_b[d];
#pragma unroll
        for (int rt = 0; rt < 4; ++rt) {
#pragma unroll
            for (int r = 0; r < 4; ++r) {
                int row = rt * 16 + q * 4 + r;
                int ra = row0 + row; int rc = (ra < NNODES) ? ra : NNODES - 1;
                float v = cm[rt][r] + agg[(size_t)rc * 64 + d] * invdeg[rc] + cb;
                if (ra < NNODES) agg[(size_t)ra * 64 + d] = 0.0f;  // ready for next iter
                v = fmaxf(v, 0.0f);
                unsigned short hi = f2bf(v);
                unsigned short lo = f2bf(v - bf2f(hi));
                Ms[row * WS + d] = hi;
                Ms[row * WS + 64 + d] = hi;
                Ms[row * WS + 128 + d] = lo;
            }
        }
    }
    __syncthreads();
    // restage Bs <- wih
#pragma unroll
    for (int j = 0; j < 18; ++j) {
        int idx = tid + 256 * j;
        int r = idx / 24, jj = idx % 24;
        *reinterpret_cast<uint4*>(&Bs[r * WS + jj * 8]) =
            *reinterpret_cast<const uint4*>(&Wcat[(size_t)(64 + r) * 192 + jj * 8]);
    }
    __syncthreads();
    // phase 3: gi = m @ wih.T  +  GRU epilogue
    floatx4 gi[4][3];
#pragma unroll
    for (int rt = 0; rt < 4; ++rt)
#pragma unroll
        for (int g = 0; g < 3; ++g)
#pragma unroll
            for (int r = 0; r < 4; ++r) gi[rt][g][r] = 0.0f;
#pragma unroll
    for (int ks = 0; ks < 6; ++ks) {
        bf16x8 b[3];
#pragma unroll
        for (int g = 0; g < 3; ++g)
            b[g] = *reinterpret_cast<const bf16x8*>(&Bs[(g * 64 + d) * WS + ks * 32 + q * 8]);
#pragma unroll
        for (int rt = 0; rt < 4; ++rt) {
            bf16x8 a = *reinterpret_cast<const bf16x8*>(&Ms[(rt * 16 + mi) * WS + ks * 32 + q * 8]);
#pragma unroll
            for (int g = 0; g < 3; ++g)
                gi[rt][g] = __builtin_amdgcn_mfma_f32_16x16x32_bf16(a, b[g], gi[rt][g], 0, 0, 0);
        }
    }
    const float bi_r = bih[d], bi_z = bih[64 + d], bi_n = bih[128 + d];
    const float bh_r = bhh[d], bh_z = bhh[64 + d], bh_n = bhh[128 + d];
#pragma unroll
    for (int rt = 0; rt < 4; ++rt) {
#pragma unroll
        for (int r = 0; r < 4; ++r) {
            int row = rt * 16 + q * 4 + r;
            int ra = row0 + row;
            float rr = sigmoidf_(gi[rt][0][r] + bi_r + gh[rt][0][r] + bh_r);
            float zz = sigmoidf_(gi[rt][1][r] + bi_z + gh[rt][1][r] + bh_z);
            float nc = tanhf(gi[rt][2][r] + bi_n + rr * (gh[rt][2][r] + bh_n));
            float hn = (1.0f - zz) * nc + zz * ho[row * 68 + d];
            if (ra < NNODES) {
                out[(size_t)ra * 64 + d] = hn;
                write_split(Abf + (size_t)ra * 192, d, hn);
            }
        }
    }
}

// Set2Set LSTM step (1 block), used ONCE for iteration 0 (q_star = 0).
__global__ __launch_bounds__(256) void k_lstm(const float* __restrict__ wih,
                                              const float* __restrict__ whh,
                                              const float* __restrict__ bih,
                                              const float* __restrict__ bhh,
                                              float* __restrict__ hl,
                                              float* __restrict__ cl,
                                              float* __restrict__ r_vec,
                                              float* __restrict__ S) {
    __shared__ float qs[128];
    __shared__ float gs[256];
    int tid = threadIdx.x;
    if (tid < 64) qs[tid] = hl[tid];
    else if (tid < 128) qs[tid] = 0.0f;
    __syncthreads();
    float g = bih[tid] + bhh[tid];
    for (int k = 0; k < 128; ++k) g += qs[k] * wih[tid * 128 + k];
    for (int k = 0; k < 64; ++k) g += qs[k] * whh[tid * 64 + k];
    gs[tid] = g;
    __syncthreads();
    if (tid < 64) {
        float ig = sigmoidf_(gs[tid]);
        float fg = sigmoidf_(gs[64 + tid]);
        float gg = tanhf(gs[128 + tid]);
        float og = sigmoidf_(gs[192 + tid]);
        float c = fg * cl[tid] + ig * gg;
        cl[tid] = c;
        hl[tid] = og * tanhf(c);
        r_vec[tid] = 0.0f;
        if (tid == 0) S[0] = 0.0f;
    }
}

// fused attention + last-block LSTM epilogue. 40 blocks; after a block's r_vec/S
// atomics it tickets `cnt`; the 40th block atomic-reads r_vec/S (device-coherent —
// intra-kernel cross-block), computes the next LSTM step (if do_lstm), writes
// hl/cl and resets r_vec/S/cnt with plain stores (visible to next launch via
// kernel-boundary release/acquire).
__global__ __launch_bounds__(256) void k_att(const float* __restrict__ out,
                                             float* __restrict__ hl,
                                             float* __restrict__ cl,
                                             float* __restrict__ r_vec,
                                             float* __restrict__ S,
                                             int* __restrict__ cnt,
                                             const float* __restrict__ wih,
                                             const float* __restrict__ whh,
                                             const float* __restrict__ bih,
                                             const float* __restrict__ bhh,
                                             int do_lstm) {
    __shared__ float qs[128];
    __shared__ float wsh[256];
    __shared__ float red[256];
    __shared__ int lastflag;
    int tid = threadIdx.x;
    if (tid < 64) qs[tid] = hl[tid];
    __syncthreads();
    int n = blockIdx.x * 256 + tid;
    float w = 0.0f;
    if (n < NNODES) {
        const float4* row = reinterpret_cast<const float4*>(out + (size_t)n * 64);
        const float4* qv = reinterpret_cast<const float4*>(qs);
        float e = 0.0f;
#pragma unroll
        for (int k = 0; k < 16; ++k) {
            float4 a = row[k], b = qv[k];
            e += a.x * b.x + a.y * b.y + a.z * b.z + a.w * b.w;
        }
        w = expf(e);
    }
    wsh[tid] = w;
    red[tid] = w;
    __syncthreads();
    for (int s = 128; s > 0; s >>= 1) {
        if (tid < s) red[tid] += red[tid + s];
        __syncthreads();
    }
    if (tid == 0) atomicAdd(S, red[0]);
    const int ln = tid >> 6, dd = tid & 63;
    float a = 0.0f;
    for (int j = 0; j < 64; ++j) {
        int nn = blockIdx.x * 256 + ln * 64 + j;
        float ov = (nn < NNODES) ? out[(size_t)nn * 64 + dd] : 0.0f;
        a += wsh[ln * 64 + j] * ov;
    }
    atomicAdd(&r_vec[dd], a);
    // completion ticket
    __syncthreads();
    if (tid == 0) {
        __threadfence();
        int t = atomicAdd(cnt, 1);
        lastflag = (t == gridDim.x - 1);
    }
    __syncthreads();
    if (!lastflag) return;
    // last block: gather r_vec/S via coherent atomic reads
    if (tid == 0) __threadfence();
    __syncthreads();
    if (do_lstm) {
        float* qs2 = qs;      // reuse shared
        float* gs = wsh;
        float Sv;
        __shared__ float Svs;
        if (tid == 0) { Sv = atomicAdd(S, 0.0f); Svs = Sv; }
        if (tid < 64) {
            float rv = atomicAdd(&r_vec[tid], 0.0f);
            red[tid] = rv;    // stash
            qs2[tid] = hl[tid];
        }
        __syncthreads();
        if (tid >= 64 && tid < 128) qs2[tid] = red[tid - 64] / Svs;
        __syncthreads();
        float g = bih[tid] + bhh[tid];
        for (int k = 0; k < 128; ++k) g += qs2[k] * wih[tid * 128 + k];
        for (int k = 0; k < 64; ++k) g += qs2[k] * whh[tid * 64 + k];
        gs[tid] = g;
        __syncthreads();
        if (tid < 64) {
            float ig = sigmoidf_(gs[tid]);
            float fg = sigmoidf_(gs[64 + tid]);
            float gg = tanhf(gs[128 + tid]);
            float og = sigmoidf_(gs[192 + tid]);
            float c = fg * cl[tid] + ig * gg;
            cl[tid] = c;
            hl[tid] = og * tanhf(c);
            r_vec[tid] = 0.0f;
            if (tid == 0) S[0] = 0.0f;
        }
    }
    if (tid == 0) *cnt = 0;
}

__global__ __launch_bounds__(128) void k_out(const float* __restrict__ hl,
                                             const float* __restrict__ r_vec,
                                             const float* __restrict__ S,
                                             const float* __restrict__ lin1_w,
                                             const float* __restrict__ lin1_b,
                                             const float* __restrict__ lin3_w,
                                             const float* __restrict__ lin3_b,
                                             float* __restrict__ dout) {
    __shared__ float qs[128];
    __shared__ float hs[64];
    int tid = threadIdx.x;
    qs[tid] = (tid < 64) ? hl[tid] : r_vec[tid - 64] / S[0];
    __syncthreads();
    if (tid < 64) {
        float a = lin1_b[tid];
        for (int k = 0; k < 128; ++k) a += qs[k] * lin1_w[tid * 128 + k];
        hs[tid] = fmaxf(a, 0.0f);
    }
    __syncthreads();
    if (tid == 0) {
        float a = lin3_b[0];
        for (int k = 0; k < 64; ++k) a += hs[k] * lin3_w[k];
        dout[0] = a;
    }
}

extern "C" void kernel_launch(void* const* d_in, const int* in_sizes, int n_in,
                              void* d_out, int out_size, void* d_ws, size_t ws_size,
                              hipStream_t stream) {
    const float* x         = (const float*)d_in[0];
    const float* edge_attr = (const float*)d_in[1];
    const int*   ei        = (const int*)d_in[2];
    const float* lin0_w    = (const float*)d_in[4];
    const float* lin0_b    = (const float*)d_in[5];
    const float* em1_w     = (const float*)d_in[6];
    const float* em1_b     = (const float*)d_in[7];
    const float* em2_w     = (const float*)d_in[8];
    const float* em2_b     = (const float*)d_in[9];
    const float* root_w    = (const float*)d_in[10];
    const float* conv_b    = (const float*)d_in[11];
    const float* gru_wih   = (const float*)d_in[12];
    const float* gru_whh   = (const float*)d_in[13];
    const float* gru_bih   = (const float*)d_in[14];
    const float* gru_bhh   = (const float*)d_in[15];
    const float* lstm_wih  = (const float*)d_in[16];
    const float* lstm_whh  = (const float*)d_in[17];
    const float* lstm_bih  = (const float*)d_in[18];
    const float* lstm_bhh  = (const float*)d_in[19];
    const float* lin1_w    = (const float*)d_in[20];
    const float* lin1_b    = (const float*)d_in[21];
    const float* lin3_w    = (const float*)d_in[22];
    const float* lin3_b    = (const float*)d_in[23];

    float* ws = (float*)d_ws;
    size_t off = 0;
    unsigned short* Mb   = (unsigned short*)(ws + off); off += (size_t)NNODES * MC / 2;  // bf16 M
    unsigned short* Abf  = (unsigned short*)(ws + off); off += (size_t)NNODES * 192 / 2;
    unsigned short* Bbf  = (unsigned short*)(ws + off); off += (size_t)MC * 192 / 2;
    unsigned short* Wcat = (unsigned short*)(ws + off); off += (size_t)448 * 192 / 2;
    float* h1s   = ws + off; off += (size_t)NEDGES * 64;
    float* outb  = ws + off; off += (size_t)NNODES * 64;
    float* agg   = ws + off; off += (size_t)NNODES * 64;
    float* deg   = ws + off; off += NNODES;   // deg, counts, cursor contiguous (one memset)
    int*   counts    = (int*)(ws + off); off += NNODES;
    int*   cursor    = (int*)(ws + off); off += NNODES;
    int*   row_start = (int*)(ws + off); off += NNODES + 4;
    int*   sortpos   = (int*)(ws + off); off += NEDGES;
    int*   dst_s     = (int*)(ws + off); off += NEDGES;
    float* invd  = ws + off; off += NNODES;
    float* r_vec = ws + off; off += 64;   // contiguous s2s state: r_vec, hl, cl, S, cnt
    float* hl    = ws + off; off += 64;
    float* cl    = ws + off; off += 64;
    float* S     = ws + off; off += 4;
    int*   cnt   = (int*)(ws + off); off += 4;

    k_node_init<<<2500, 256, 0, stream>>>(x, lin0_w, lin0_b, outb, Abf);
    k_wtab<<<1152, 256, 0, stream>>>(em2_w, em2_b, root_w, gru_wih, gru_whh, Bbf, Wcat);
    hipMemsetAsync(deg, 0, 3 * NNODES * sizeof(float), stream);
    hipMemsetAsync(agg, 0, (size_t)NNODES * 64 * sizeof(float), stream);  // iter-0 agg
    k_hist<<<(NEDGES + 255) / 256, 256, 0, stream>>>(ei, counts, deg);
    k_scan<<<1, 256, 0, stream>>>(counts, row_start, cursor, deg, invd);
    k_scatter<<<(NEDGES + 255) / 256, 256, 0, stream>>>(ei, cursor, sortpos, dst_s);
    k_h1<<<10000, 256, 0, stream>>>(edge_attr, em1_w, em1_b, sortpos, h1s);

    for (int t = 0; t < 6; ++t) {
        k_gemmM<<<dim3(65, 157), 256, 0, stream>>>(Abf, Bbf, Mb);
        k_msg<<<2500, 256, 0, stream>>>(Mb, h1s, row_start, dst_s, agg);
        k_node<<<157, 256, 0, stream>>>(agg, invd, Wcat, conv_b, gru_bih, gru_bhh,
                                        outb, Abf);
    }

    hipMemsetAsync(r_vec, 0, (64 + 64 + 64 + 4 + 4) * sizeof(float), stream);  // r_vec,hl,cl,S,cnt
    k_lstm<<<1, 256, 0, stream>>>(lstm_wih, lstm_whh, lstm_bih, lstm_bhh, hl, cl, r_vec, S);
    for (int it = 0; it < 6; ++it) {
        k_att<<<40, 256, 0, stream>>>(outb, hl, cl, r_vec, S, cnt,
                                      lstm_wih, lstm_whh, lstm_bih, lstm_bhh,
                                      (it < 5) ? 1 : 0);
    }
    k_out<<<1, 128, 0, stream>>>(hl, r_vec, S, lin1_w, lin1_b, lin3_w, lin3_b, (float*)d_out);
}

// Round 17
// 720.461 us; speedup vs baseline: 1.0118x; 1.0118x over previous
//
#include <hip/hip_runtime.h>
#include <math.h>

#define NNODES 10000
#define NEDGES 40000
#define DIM 64
#define MC 4160     // 4096 h1-contraction cols + 64 bias cols
#define WS 200      // LDS row stride (ushorts) for 192-k bf16 tiles (k_node)
#define AST2 72     // LDS row stride (ushorts) for 64-k bf16 tiles (k_gemmM)

typedef short bf16x8 __attribute__((ext_vector_type(8)));
typedef float floatx4 __attribute__((ext_vector_type(4)));

__device__ __forceinline__ float sigmoidf_(float x) { return 1.0f / (1.0f + expf(-x)); }

// float -> bf16 (RNE), returned as raw ushort
__device__ __forceinline__ unsigned short f2bf(float x) {
    unsigned int u = __float_as_uint(x);
    u += 0x7fffu + ((u >> 16) & 1u);
    return (unsigned short)(u >> 16);
}
__device__ __forceinline__ float bf2f(unsigned short h) {
    return __uint_as_float(((unsigned int)h) << 16);
}
// write split [hi | hi | lo] at row base (A_cat layout for K=192 bf16 GEMM)
__device__ __forceinline__ void write_split(unsigned short* __restrict__ p, int d, float v) {
    unsigned short hi = f2bf(v);
    unsigned short lo = f2bf(v - bf2f(hi));
    p[d] = hi;
    p[64 + d] = hi;
    p[128 + d] = lo;
}

// out0 = relu(x @ lin0_w.T + lin0_b)   [N,64] ; also writes bf16-split A rows
__global__ __launch_bounds__(256) void k_node_init(const float* __restrict__ x,
                                                   const float* __restrict__ w,
                                                   const float* __restrict__ b,
                                                   float* __restrict__ out,
                                                   unsigned short* __restrict__ Abf) {
    int idx = blockIdx.x * 256 + threadIdx.x;
    if (idx >= NNODES * 64) return;
    int n = idx >> 6, d = idx & 63;
    float a = b[d];
    a += x[n * 3 + 0] * w[d * 3 + 0];
    a += x[n * 3 + 1] * w[d * 3 + 1];
    a += x[n * 3 + 2] * w[d * 3 + 2];
    float v = fmaxf(a, 0.0f);
    out[idx] = v;
    write_split(Abf + (size_t)n * 192, d, v);
}

// h1 = relu(edge_attr @ em1_w.T + em1_b), written at src-sorted position
__global__ __launch_bounds__(256) void k_h1(const float* __restrict__ ea,
                                            const float* __restrict__ w,
                                            const float* __restrict__ b,
                                            const int* __restrict__ sortpos,
                                            float* __restrict__ h1s) {
    int idx = blockIdx.x * 256 + threadIdx.x;
    if (idx >= NEDGES * 64) return;
    int e = idx >> 6, d = idx & 63;
    float a = b[d];
#pragma unroll
    for (int j = 0; j < 7; ++j) a += ea[e * 7 + j] * w[d * 7 + j];
    h1s[(size_t)sortpos[e] * 64 + d] = fmaxf(a, 0.0f);
}

// B_cat (bf16 split, transposed): Bbf[c][0:64]=hi(W2[:,c]), [64:128]=lo, [128:192]=hi
// k_gemmM (plain-bf16 K=64) reads only the first 64 columns (the hi parts).
__global__ __launch_bounds__(256) void k_w2bt(const float* __restrict__ em2_w,
                                              const float* __restrict__ em2_b,
                                              unsigned short* __restrict__ Bbf) {
    int idx = blockIdx.x * 256 + threadIdx.x;
    if (idx >= 64 * MC) return;
    int c = idx >> 6, i = idx & 63;
    float v;
    if (c < 4096) {
        v = em2_w[((size_t)(i * 64 + (c >> 6))) * 64 + (c & 63)];
    } else {
        v = em2_b[i * 64 + (c - 4096)];
    }
    unsigned short hi = f2bf(v);
    unsigned short lo = f2bf(v - bf2f(hi));
    unsigned short* row = Bbf + (size_t)c * 192;
    row[i] = hi;
    row[64 + i] = lo;
    row[128 + i] = hi;
}

// Wcat: B_cat split tables for the node-update GEMMs.
__global__ __launch_bounds__(256) void k_wb(const float* __restrict__ root_w,
                                            const float* __restrict__ wih,
                                            const float* __restrict__ whh,
                                            unsigned short* __restrict__ Wcat) {
    int idx = blockIdx.x * 256 + threadIdx.x;
    if (idx >= 448 * 64) return;
    int r = idx >> 6, i = idx & 63;
    float v;
    if (r < 64) v = root_w[i * 64 + r];
    else if (r < 256) v = wih[(r - 64) * 64 + i];
    else v = whh[(r - 256) * 64 + i];
    unsigned short hi = f2bf(v);
    unsigned short lo = f2bf(v - bf2f(hi));
    unsigned short* row = Wcat + (size_t)r * 192;
    row[i] = hi;
    row[64 + i] = lo;
    row[128 + i] = hi;
}

// src histogram (for CSR sort) + dst degree (for mean)
__global__ __launch_bounds__(256) void k_hist(const int* __restrict__ ei,
                                              int* __restrict__ counts,
                                              float* __restrict__ deg) {
    int e = blockIdx.x * 256 + threadIdx.x;
    if (e < NEDGES) {
        atomicAdd(&counts[ei[e]], 1);
        atomicAdd(&deg[ei[NEDGES + e]], 1.0f);
    }
}

// single-block 2-phase exclusive scan: per-thread serial prefix over a 40-elem
// chunk (registers), one 8-step Hillis-Steele over 256 partials, write-back.
// 16 barriers total (was ~640).
__global__ __launch_bounds__(256) void k_scan(const int* __restrict__ counts,
                                              int* __restrict__ row_start,
                                              int* __restrict__ cursor) {
    __shared__ int partial[256];
    const int tid = threadIdx.x;
    const int base = tid * 40;            // 256*40 = 10240 >= NNODES
    int local[40];
    int sum = 0;
#pragma unroll
    for (int i = 0; i < 40; ++i) {
        int idx = base + i;
        int v = (idx < NNODES) ? counts[idx] : 0;
        local[i] = sum;
        sum += v;
    }
    partial[tid] = sum;
    __syncthreads();
    for (int off = 1; off < 256; off <<= 1) {
        int t = (tid >= off) ? partial[tid - off] : 0;
        __syncthreads();
        partial[tid] += t;
        __syncthreads();
    }
    const int prev = (tid > 0) ? partial[tid - 1] : 0;
#pragma unroll
    for (int i = 0; i < 40; ++i) {
        int idx = base + i;
        if (idx < NNODES) {
            int rs = prev + local[i];
            row_start[idx] = rs;
            cursor[idx] = rs;
        }
    }
    if (tid == 255) row_start[NNODES] = partial[255];
}

__global__ __launch_bounds__(256) void k_scatter(const int* __restrict__ ei,
                                                 int* __restrict__ cursor,
                                                 int* __restrict__ sortpos,
                                                 int* __restrict__ dst_s) {
    int e = blockIdx.x * 256 + threadIdx.x;
    if (e < NEDGES) {
        int s = ei[e];
        int pos = atomicAdd(&cursor[s], 1);
        sortpos[e] = pos;
        dst_s[pos] = ei[NEDGES + e];
    }
}

__global__ __launch_bounds__(256) void k_invdeg(const float* __restrict__ deg, float* __restrict__ inv) {
    int n = blockIdx.x * 256 + threadIdx.x;
    if (n < NNODES) {
        float dg = deg[n];
        inv[n] = dg > 0.0f ? 1.0f / dg : 0.0f;
    }
}

// M[10000, 4160] = out @ W2 via plain-bf16 MFMA, K=64, WITH coalesced LDS staging
// (round-13 showed direct global fragment gathers lose). Stage only the 64
// hi-columns of A/B split rows; C-tile overlays the staging buffer for the
// packed-bf16 epilogue. LDS = 18.4 KB -> high occupancy.
__global__ __launch_bounds__(256) void k_gemmM(const unsigned short* __restrict__ Abf,
                                               const unsigned short* __restrict__ Bbf,
                                               unsigned short* __restrict__ Mb) {
    __shared__ __align__(16) unsigned short smem[2 * 64 * AST2];  // 18432 B
    unsigned short* As = smem;
    unsigned short* Bs = smem + 64 * AST2;
    const int tid = threadIdx.x;
    const int col0 = blockIdx.x * 64;
    const int row0 = blockIdx.y * 64;
    // stage A and B hi-tiles: 64 rows x 64 ushorts each = 512 uint4 chunks each
#pragma unroll
    for (int j = 0; j < 2; ++j) {
        int idx = tid + 256 * j;       // 0..511
        int r = idx >> 3, c8 = (idx & 7) * 8;
        int ra = row0 + r;
        if (ra >= NNODES) ra = NNODES - 1;
        *reinterpret_cast<uint4*>(&As[r * AST2 + c8]) =
            *reinterpret_cast<const uint4*>(&Abf[(size_t)ra * 192 + c8]);
        *reinterpret_cast<uint4*>(&Bs[r * AST2 + c8]) =
            *reinterpret_cast<const uint4*>(&Bbf[(size_t)(col0 + r) * 192 + c8]);
    }
    __syncthreads();
    const int wave = tid >> 6, lane = tid & 63;
    const int mi = lane & 15, q = lane >> 4;
    floatx4 acc[4];
#pragma unroll
    for (int nt = 0; nt < 4; ++nt)
#pragma unroll
        for (int r = 0; r < 4; ++r) acc[nt][r] = 0.0f;
    const unsigned short* arow = &As[(wave * 16 + mi) * AST2 + q * 8];
#pragma unroll
    for (int ks = 0; ks < 2; ++ks) {
        bf16x8 a = *reinterpret_cast<const bf16x8*>(arow + ks * 32);
#pragma unroll
        for (int nt = 0; nt < 4; ++nt) {
            bf16x8 b = *reinterpret_cast<const bf16x8*>(&Bs[(nt * 16 + mi) * AST2 + ks * 32 + q * 8]);
            acc[nt] = __builtin_amdgcn_mfma_f32_16x16x32_bf16(a, b, acc[nt], 0, 0, 0);
        }
    }
    __syncthreads();  // staging reads done; overlay C-tile
    float* Cs = reinterpret_cast<float*>(smem);  // [64][68] floats = 17408 B
    const int rl = wave * 16 + q * 4;
#pragma unroll
    for (int nt = 0; nt < 4; ++nt)
#pragma unroll
        for (int r = 0; r < 4; ++r)
            Cs[(rl + r) * 68 + nt * 16 + mi] = acc[nt][r];
    __syncthreads();
    // pack to bf16: 64 rows x 64 cols = 512 uint4 chunks (8 ushorts each)
#pragma unroll
    for (int j = 0; j < 2; ++j) {
        int idx = tid + 256 * j;        // 0..511
        int r = idx >> 3, c8 = (idx & 7) * 8;
        int row = row0 + r;
        if (row < NNODES) {
            const float* src = &Cs[r * 68 + c8];
            unsigned int p0 = (unsigned int)f2bf(src[0]) | ((unsigned int)f2bf(src[1]) << 16);
            unsigned int p1 = (unsigned int)f2bf(src[2]) | ((unsigned int)f2bf(src[3]) << 16);
            unsigned int p2 = (unsigned int)f2bf(src[4]) | ((unsigned int)f2bf(src[5]) << 16);
            unsigned int p3 = (unsigned int)f2bf(src[6]) | ((unsigned int)f2bf(src[7]) << 16);
            *reinterpret_cast<uint4*>(&Mb[(size_t)row * MC + col0 + c8]) =
                make_uint4(p0, p1, p2, p3);
        }
    }
}

// Wave-per-src message over bf16 M: lane o holds its full M row slice (128 B =
// 8 x uint4 = 32 VGPRs), unpacks bf16 inline. No LDS, no barriers. h1 read as
// wave-uniform float4 (L1 broadcast); one coalesced 64-lane atomic row per edge.
// Packing (k_gemmM): low 16 bits = even k, high = odd k.
__global__ __launch_bounds__(256) void k_msg(const unsigned short* __restrict__ Mb,
                                             const float* __restrict__ h1s,
                                             const int* __restrict__ row_start,
                                             const int* __restrict__ dst_s,
                                             float* __restrict__ agg) {
    const int w = threadIdx.x >> 6;
    const int o = threadIdx.x & 63;
    const int s = blockIdx.x * 4 + w;
    const int e0 = row_start[s], e1 = row_start[s + 1];
    if (e0 == e1) return;
    const unsigned short* mrow = Mb + (size_t)s * MC + o * 64;
    uint4 m[8];
#pragma unroll
    for (int j = 0; j < 8; ++j)
        m[j] = *reinterpret_cast<const uint4*>(mrow + j * 8);
    const float bias = bf2f(Mb[(size_t)s * MC + 4096 + o]);
    for (int e = e0; e < e1; ++e) {
        const float4* hv = reinterpret_cast<const float4*>(h1s + (size_t)e * 64);
        float acc = bias;
#pragma unroll
        for (int j = 0; j < 8; ++j) {
            float4 ha = hv[2 * j];
            float4 hb = hv[2 * j + 1];
            unsigned int u;
            u = m[j].x;
            acc += ha.x * __uint_as_float(u << 16) + ha.y * __uint_as_float(u & 0xffff0000u);
            u = m[j].y;
            acc += ha.z * __uint_as_float(u << 16) + ha.w * __uint_as_float(u & 0xffff0000u);
            u = m[j].z;
            acc += hb.x * __uint_as_float(u << 16) + hb.y * __uint_as_float(u & 0xffff0000u);
            u = m[j].w;
            acc += hb.z * __uint_as_float(u << 16) + hb.w * __uint_as_float(u & 0xffff0000u);
        }
        atomicAdd(&agg[(size_t)dst_s[e] * 64 + o], acc);
    }
}

// MFMA node update: 64-node tile per block; 3 GEMM phases (gh, conv, gi) + GRU epilogue.
// Keeps the fp32-split K=192 path (GRU recurrence is precision-critical).
// Also zeroes agg after consuming it (replaces per-iter memset).
__global__ __launch_bounds__(256) void k_node(float* __restrict__ agg,
                                              const float* __restrict__ invdeg,
                                              const unsigned short* __restrict__ Wcat,
                                              const float* __restrict__ conv_b,
                                              const float* __restrict__ bih,
                                              const float* __restrict__ bhh,
                                              float* __restrict__ out,
                                              unsigned short* __restrict__ Abf) {
    __shared__ unsigned short As[64 * WS];   // out A_cat
    __shared__ unsigned short Ms[64 * WS];   // m A_cat (written in conv phase)
    __shared__ unsigned short Bs[192 * WS];  // weight B_cat staging (whh -> root -> wih)
    __shared__ float ho[64 * 68];            // exact f32 h_old
    const int tid = threadIdx.x;
    const int row0 = blockIdx.x * 64;
#pragma unroll
    for (int j = 0; j < 6; ++j) {
        int idx = tid + 256 * j;
        int r = idx / 24, jj = idx % 24;
        int ra = row0 + r; if (ra >= NNODES) ra = NNODES - 1;
        *reinterpret_cast<uint4*>(&As[r * WS + jj * 8]) =
            *reinterpret_cast<const uint4*>(&Abf[(size_t)ra * 192 + jj * 8]);
    }
#pragma unroll
    for (int j = 0; j < 4; ++j) {
        int idx = tid + 256 * j;
        int r = idx >> 4, c4 = (idx & 15) * 4;
        int ra = row0 + r; if (ra >= NNODES) ra = NNODES - 1;
        *reinterpret_cast<float4*>(&ho[r * 68 + c4]) =
            *reinterpret_cast<const float4*>(&out[(size_t)ra * 64 + c4]);
    }
#pragma unroll
    for (int j = 0; j < 18; ++j) {
        int idx = tid + 256 * j;
        int r = idx / 24, jj = idx % 24;
        *reinterpret_cast<uint4*>(&Bs[r * WS + jj * 8]) =
            *reinterpret_cast<const uint4*>(&Wcat[(size_t)(256 + r) * 192 + jj * 8]);
    }
    __syncthreads();
    const int wave = tid >> 6, lane = tid & 63;
    const int mi = lane & 15, q = lane >> 4;
    const int d = wave * 16 + mi;
    // phase 1: gh = out @ whh.T for gate cols {d, 64+d, 128+d}
    floatx4 gh[4][3];
#pragma unroll
    for (int rt = 0; rt < 4; ++rt)
#pragma unroll
        for (int g = 0; g < 3; ++g)
#pragma unroll
            for (int r = 0; r < 4; ++r) gh[rt][g][r] = 0.0f;
#pragma unroll
    for (int ks = 0; ks < 6; ++ks) {
        bf16x8 b[3];
#pragma unroll
        for (int g = 0; g < 3; ++g)
            b[g] = *reinterpret_cast<const bf16x8*>(&Bs[(g * 64 + d) * WS + ks * 32 + q * 8]);
#pragma unroll
        for (int rt = 0; rt < 4; ++rt) {
            bf16x8 a = *reinterpret_cast<const bf16x8*>(&As[(rt * 16 + mi) * WS + ks * 32 + q * 8]);
#pragma unroll
            for (int g = 0; g < 3; ++g)
                gh[rt][g] = __builtin_amdgcn_mfma_f32_16x16x32_bf16(a, b[g], gh[rt][g], 0, 0, 0);
        }
    }
    __syncthreads();
    // restage Bs <- root
#pragma unroll
    for (int j = 0; j < 6; ++j) {
        int idx = tid + 256 * j;
        int r = idx / 24, jj = idx % 24;
        *reinterpret_cast<uint4*>(&Bs[r * WS + jj * 8]) =
            *reinterpret_cast<const uint4*>(&Wcat[(size_t)r * 192 + jj * 8]);
    }
    __syncthreads();
    // phase 2: m = relu(out@root + agg*invd + conv_b) -> Ms (A_cat split); zero agg
    {
        floatx4 cm[4];
#pragma unroll
        for (int rt = 0; rt < 4; ++rt)
#pragma unroll
            for (int r = 0; r < 4; ++r) cm[rt][r] = 0.0f;
#pragma unroll
        for (int ks = 0; ks < 6; ++ks) {
            bf16x8 b = *reinterpret_cast<const bf16x8*>(&Bs[d * WS + ks * 32 + q * 8]);
#pragma unroll
            for (int rt = 0; rt < 4; ++rt) {
                bf16x8 a = *reinterpret_cast<const bf16x8*>(&As[(rt * 16 + mi) * WS + ks * 32 + q * 8]);
                cm[rt] = __builtin_amdgcn_mfma_f32_16x16x32_bf16(a, b, cm[rt], 0, 0, 0);
            }
        }
        const float cb = conv_b[d];
#pragma unroll
        for (int rt = 0; rt < 4; ++rt) {
#pragma unroll
            for (int r = 0; r < 4; ++r) {
                int row = rt * 16 + q * 4 + r;
                int ra = row0 + row; int rc = (ra < NNODES) ? ra : NNODES - 1;
                float v = cm[rt][r] + agg[(size_t)rc * 64 + d] * invdeg[rc] + cb;
                if (ra < NNODES) agg[(size_t)ra * 64 + d] = 0.0f;  // ready for next iter
                v = fmaxf(v, 0.0f);
                unsigned short hi = f2bf(v);
                unsigned short lo = f2bf(v - bf2f(hi));
                Ms[row * WS + d] = hi;
                Ms[row * WS + 64 + d] = hi;
                Ms[row * WS + 128 + d] = lo;
            }
        }
    }
    __syncthreads();
    // restage Bs <- wih
#pragma unroll
    for (int j = 0; j < 18; ++j) {
        int idx = tid + 256 * j;
        int r = idx / 24, jj = idx % 24;
        *reinterpret_cast<uint4*>(&Bs[r * WS + jj * 8]) =
            *reinterpret_cast<const uint4*>(&Wcat[(size_t)(64 + r) * 192 + jj * 8]);
    }
    __syncthreads();
    // phase 3: gi = m @ wih.T  +  GRU epilogue
    floatx4 gi[4][3];
#pragma unroll
    for (int rt = 0; rt < 4; ++rt)
#pragma unroll
        for (int g = 0; g < 3; ++g)
#pragma unroll
            for (int r = 0; r < 4; ++r) gi[rt][g][r] = 0.0f;
#pragma unroll
    for (int ks = 0; ks < 6; ++ks) {
        bf16x8 b[3];
#pragma unroll
        for (int g = 0; g < 3; ++g)
            b[g] = *reinterpret_cast<const bf16x8*>(&Bs[(g * 64 + d) * WS + ks * 32 + q * 8]);
#pragma unroll
        for (int rt = 0; rt < 4; ++rt) {
            bf16x8 a = *reinterpret_cast<const bf16x8*>(&Ms[(rt * 16 + mi) * WS + ks * 32 + q * 8]);
#pragma unroll
            for (int g = 0; g < 3; ++g)
                gi[rt][g] = __builtin_amdgcn_mfma_f32_16x16x32_bf16(a, b[g], gi[rt][g], 0, 0, 0);
        }
    }
    const float bi_r = bih[d], bi_z = bih[64 + d], bi_n = bih[128 + d];
    const float bh_r = bhh[d], bh_z = bhh[64 + d], bh_n = bhh[128 + d];
#pragma unroll
    for (int rt = 0; rt < 4; ++rt) {
#pragma unroll
        for (int r = 0; r < 4; ++r) {
            int row = rt * 16 + q * 4 + r;
            int ra = row0 + row;
            float rr = sigmoidf_(gi[rt][0][r] + bi_r + gh[rt][0][r] + bh_r);
            float zz = sigmoidf_(gi[rt][1][r] + bi_z + gh[rt][1][r] + bh_z);
            float nc = tanhf(gi[rt][2][r] + bi_n + rr * (gh[rt][2][r] + bh_n));
            float hn = (1.0f - zz) * nc + zz * ho[row * 68 + d];
            if (ra < NNODES) {
                out[(size_t)ra * 64 + d] = hn;
                write_split(Abf + (size_t)ra * 192, d, hn);
            }
        }
    }
}

// Set2Set LSTM step (1 block). iter>0: q_star tail = r/S from prev attention.
__global__ __launch_bounds__(256) void k_lstm(const float* __restrict__ wih,
                                              const float* __restrict__ whh,
                                              const float* __restrict__ bih,
                                              const float* __restrict__ bhh,
                                              float* __restrict__ hl,
                                              float* __restrict__ cl,
                                              float* __restrict__ r_vec,
                                              float* __restrict__ S,
                                              int iter) {
    __shared__ float qs[128];
    __shared__ float gs[256];
    int tid = threadIdx.x;
    if (tid < 64) qs[tid] = hl[tid];
    else if (tid < 128) qs[tid] = (iter > 0) ? r_vec[tid - 64] / S[0] : 0.0f;
    __syncthreads();
    float g = bih[tid] + bhh[tid];
    for (int k = 0; k < 128; ++k) g += qs[k] * wih[tid * 128 + k];
    for (int k = 0; k < 64; ++k) g += qs[k] * whh[tid * 64 + k];
    gs[tid] = g;
    __syncthreads();
    if (tid < 64) {
        float ig = sigmoidf_(gs[tid]);
        float fg = sigmoidf_(gs[64 + tid]);
        float gg = tanhf(gs[128 + tid]);
        float og = sigmoidf_(gs[192 + tid]);
        float c = fg * cl[tid] + ig * gg;
        cl[tid] = c;
        hl[tid] = og * tanhf(c);
        r_vec[tid] = 0.0f;
        if (tid == 0) S[0] = 0.0f;
    }
}

// fused attention: logits+exp+S-sum AND weighted readout in one pass over `out`
__global__ __launch_bounds__(256) void k_att(const float* __restrict__ out,
                                             const float* __restrict__ q,
                                             float* __restrict__ r_vec,
                                             float* __restrict__ S) {
    __shared__ float qs[64];
    __shared__ float wsh[256];
    __shared__ float red[256];
    int tid = threadIdx.x;
    if (tid < 64) qs[tid] = q[tid];
    __syncthreads();
    int n = blockIdx.x * 256 + tid;
    float w = 0.0f;
    if (n < NNODES) {
        const float4* row = reinterpret_cast<const float4*>(out + (size_t)n * 64);
        const float4* qv = reinterpret_cast<const float4*>(qs);
        float e = 0.0f;
#pragma unroll
        for (int k = 0; k < 16; ++k) {
            float4 a = row[k], b = qv[k];
            e += a.x * b.x + a.y * b.y + a.z * b.z + a.w * b.w;
        }
        w = expf(e);
    }
    wsh[tid] = w;
    red[tid] = w;
    __syncthreads();
    for (int s = 128; s > 0; s >>= 1) {
        if (tid < s) red[tid] += red[tid + s];
        __syncthreads();
    }
    if (tid == 0) atomicAdd(S, red[0]);
    const int ln = tid >> 6, dd = tid & 63;
    float a = 0.0f;
    for (int j = 0; j < 64; ++j) {
        int nn = blockIdx.x * 256 + ln * 64 + j;
        float ov = (nn < NNODES) ? out[(size_t)nn * 64 + dd] : 0.0f;
        a += wsh[ln * 64 + j] * ov;
    }
    atomicAdd(&r_vec[dd], a);
}

__global__ __launch_bounds__(128) void k_out(const float* __restrict__ hl,
                                             const float* __restrict__ r_vec,
                                             const float* __restrict__ S,
                                             const float* __restrict__ lin1_w,
                                             const float* __restrict__ lin1_b,
                                             const float* __restrict__ lin3_w,
                                             const float* __restrict__ lin3_b,
                                             float* __restrict__ dout) {
    __shared__ float qs[128];
    __shared__ float hs[64];
    int tid = threadIdx.x;
    qs[tid] = (tid < 64) ? hl[tid] : r_vec[tid - 64] / S[0];
    __syncthreads();
    if (tid < 64) {
        float a = lin1_b[tid];
        for (int k = 0; k < 128; ++k) a += qs[k] * lin1_w[tid * 128 + k];
        hs[tid] = fmaxf(a, 0.0f);
    }
    __syncthreads();
    if (tid == 0) {
        float a = lin3_b[0];
        for (int k = 0; k < 64; ++k) a += hs[k] * lin3_w[k];
        dout[0] = a;
    }
}

extern "C" void kernel_launch(void* const* d_in, const int* in_sizes, int n_in,
                              void* d_out, int out_size, void* d_ws, size_t ws_size,
                              hipStream_t stream) {
    const float* x         = (const float*)d_in[0];
    const float* edge_attr = (const float*)d_in[1];
    const int*   ei        = (const int*)d_in[2];
    const float* lin0_w    = (const float*)d_in[4];
    const float* lin0_b    = (const float*)d_in[5];
    const float* em1_w     = (const float*)d_in[6];
    const float* em1_b     = (const float*)d_in[7];
    const float* em2_w     = (const float*)d_in[8];
    const float* em2_b     = (const float*)d_in[9];
    const float* root_w    = (const float*)d_in[10];
    const float* conv_b    = (const float*)d_in[11];
    const float* gru_wih   = (const float*)d_in[12];
    const float* gru_whh   = (const float*)d_in[13];
    const float* gru_bih   = (const float*)d_in[14];
    const float* gru_bhh   = (const float*)d_in[15];
    const float* lstm_wih  = (const float*)d_in[16];
    const float* lstm_whh  = (const float*)d_in[17];
    const float* lstm_bih  = (const float*)d_in[18];
    const float* lstm_bhh  = (const float*)d_in[19];
    const float* lin1_w    = (const float*)d_in[20];
    const float* lin1_b    = (const float*)d_in[21];
    const float* lin3_w    = (const float*)d_in[22];
    const float* lin3_b    = (const float*)d_in[23];

    float* ws = (float*)d_ws;
    size_t off = 0;
    unsigned short* Mb   = (unsigned short*)(ws + off); off += (size_t)NNODES * MC / 2;  // bf16 M
    unsigned short* Abf  = (unsigned short*)(ws + off); off += (size_t)NNODES * 192 / 2;
    unsigned short* Bbf  = (unsigned short*)(ws + off); off += (size_t)MC * 192 / 2;
    unsigned short* Wcat = (unsigned short*)(ws + off); off += (size_t)448 * 192 / 2;
    float* h1s   = ws + off; off += (size_t)NEDGES * 64;
    float* outb  = ws + off; off += (size_t)NNODES * 64;
    float* agg   = ws + off; off += (size_t)NNODES * 64;
    float* deg   = ws + off; off += NNODES;   // deg, counts, cursor contiguous (one memset)
    int*   counts    = (int*)(ws + off); off += NNODES;
    int*   cursor    = (int*)(ws + off); off += NNODES;
    int*   row_start = (int*)(ws + off); off += NNODES + 4;
    int*   sortpos   = (int*)(ws + off); off += NEDGES;
    int*   dst_s     = (int*)(ws + off); off += NEDGES;
    float* invd  = ws + off; off += NNODES;
    float* r_vec = ws + off; off += 64;
    float* hl    = ws + off; off += 64;
    float* cl    = ws + off; off += 64;
    float* S     = ws + off; off += 4;

    k_node_init<<<2500, 256, 0, stream>>>(x, lin0_w, lin0_b, outb, Abf);
    k_w2bt<<<(64 * MC + 255) / 256, 256, 0, stream>>>(em2_w, em2_b, Bbf);
    k_wb<<<(448 * 64 + 255) / 256, 256, 0, stream>>>(root_w, gru_wih, gru_whh, Wcat);
    hipMemsetAsync(deg, 0, 3 * NNODES * sizeof(float), stream);
    hipMemsetAsync(agg, 0, (size_t)NNODES * 64 * sizeof(float), stream);  // iter-0 agg
    k_hist<<<(NEDGES + 255) / 256, 256, 0, stream>>>(ei, counts, deg);
    k_scan<<<1, 256, 0, stream>>>(counts, row_start, cursor);
    k_scatter<<<(NEDGES + 255) / 256, 256, 0, stream>>>(ei, cursor, sortpos, dst_s);
    k_invdeg<<<(NNODES + 255) / 256, 256, 0, stream>>>(deg, invd);
    k_h1<<<10000, 256, 0, stream>>>(edge_attr, em1_w, em1_b, sortpos, h1s);

    for (int t = 0; t < 6; ++t) {
        k_gemmM<<<dim3(65, 157), 256, 0, stream>>>(Abf, Bbf, Mb);
        k_msg<<<2500, 256, 0, stream>>>(Mb, h1s, row_start, dst_s, agg);
        k_node<<<157, 256, 0, stream>>>(agg, invd, Wcat, conv_b, gru_bih, gru_bhh,
                                        outb, Abf);
    }

    hipMemsetAsync(r_vec, 0, (64 + 64 + 64 + 1) * sizeof(float), stream);
    for (int it = 0; it < 6; ++it) {
        k_lstm<<<1, 256, 0, stream>>>(lstm_wih, lstm_whh, lstm_bih, lstm_bhh, hl, cl, r_vec, S, it);
        k_att<<<40, 256, 0, stream>>>(outb, hl, r_vec, S);
    }
    k_out<<<1, 128, 0, stream>>>(hl, r_vec, S, lin1_w, lin1_b, lin3_w, lin3_b, (float*)d_out);
}